// Round 4
// baseline (918.332 us; speedup 1.0000x reference)
//
#include <hip/hip_runtime.h>
#include <math.h>

#define TOPK 7
// dims (fixed by problem): L=S=2048, B=8, D=1024, H=16, E=64

typedef __attribute__((ext_vector_type(8))) short bf16x8;
typedef __attribute__((ext_vector_type(4))) float f32x4;

// ---------------------------------------------------------------------------
// async global->LDS, 16B per lane (wave-uniform LDS base + lane*16)
// ---------------------------------------------------------------------------
__device__ __forceinline__ void glds16(const ushort* g, ushort* l)
{
    __builtin_amdgcn_global_load_lds(
        (const __attribute__((address_space(1))) void*)g,
        (__attribute__((address_space(3))) void*)l, 16, 0, 0);
}

// ---------------------------------------------------------------------------
// fp32 -> (hi,lo) bf16 split, RN-even via bit ops. n4 = n/4.
// ---------------------------------------------------------------------------
__device__ __forceinline__ void split1(float x, ushort& h, ushort& lo)
{
    union U { float f; unsigned u; };
    U a; a.f = x;
    unsigned r = (a.u + 0x7FFFu + ((a.u >> 16) & 1u)) >> 16;
    h = (ushort)r;
    U b; b.u = r << 16;
    U d; d.f = x - b.f;
    unsigned r2 = (d.u + 0x7FFFu + ((d.u >> 16) & 1u)) >> 16;
    lo = (ushort)r2;
}

__global__ __launch_bounds__(256)
void split_f32(const float* __restrict__ x, ushort* __restrict__ hi,
               ushort* __restrict__ lo, int n4)
{
    for (int i = blockIdx.x * 256 + threadIdx.x; i < n4; i += gridDim.x * 256) {
        float4 v = ((const float4*)x)[i];
        ushort4 h, lw;
        split1(v.x, h.x, lw.x);
        split1(v.y, h.y, lw.y);
        split1(v.z, h.z, lw.z);
        split1(v.w, h.w, lw.w);
        ((ushort4*)hi)[i] = h;
        ((ushort4*)lo)[i] = lw;
    }
}

// ---------------------------------------------------------------------------
// split-bf16 NT GEMM: C[M,1024] = A[M,1024]*B[1024,1024]^T + bias
// A,B given as (hi,lo) bf16 pairs. C fp32.
//
// 256x256 tile, BK=32, 512 thr (8 waves as 2M x 4N; wave tile 128x64 =
// 8x4 frags of 16x16). 3 MFMAs per frag-pair: Ah*Bh + Ah*Bl + Al*Bh.
// FP accumulation order per acc element identical to previous rounds.
//
// Pipeline (T3+T4+T5): 2 LDS buffers (2 x 64KB), RAW s_barrier + counted
// vmcnt. Per K-step:
//   compute(buf[t&1])  ->  barrier(#1: all reads of buf done)
//   STAGE(tile t+2 into buf[t&1])  (8 glds/wave, stays IN FLIGHT)
//   s_waitcnt vmcnt(8)   <- waits for tile t+1 (issued one FULL compute
//                           phase ago); the 8 just-issued loads remain
//                           outstanding across the barrier (never vmcnt(0)
//                           in the main loop -- the T4 discipline)
//   barrier(#2: tile t+1 resident for everyone)
// setprio(1) around the MFMA cluster (T5).
// NOTE (round-3 bug): STAGE's former inner loop var `t` shadowed the K-loop
// `t` in the macro args ((t&1)*32768, (t+2)*32) -> staged garbage. Args are
// now snapshotted into _bb/_kk and the inner var is `st`.
// ---------------------------------------------------------------------------
__global__ __launch_bounds__(512, 2)
void gemm_split(const ushort* __restrict__ Ah, const ushort* __restrict__ Al,
                const ushort* __restrict__ Bh, const ushort* __restrict__ Bl,
                const float* __restrict__ bias, float* __restrict__ C)
{
    __shared__ ushort lds[65536];   // 2 buffers x 64KB = 128KB
    const int tid = threadIdx.x;
    const int w = tid >> 6, l = tid & 63;

    // T1 swizzle: ord%8 == XCD (round-robin dispatch); nwg divisible by 8.
    const int ord = blockIdx.y * gridDim.x + blockIdx.x;
    const int cpx = (gridDim.x * gridDim.y) >> 3;
    const int swz = (ord & 7) * cpx + (ord >> 3);
    const int bx = swz & 3;          // gridDim.x == 4 (N tiles of 256)
    const int by = swz >> 2;         // M tile

    const int wm = w >> 2, wn = w & 3;      // 2M x 4N waves
    const int lr = l & 15, kgr = l >> 4;

    // staging map: s = w*8 + st in [0,64): comp = s>>4 (0=Ah,1=Al,2=Bh,3=Bl),
    // kg = (s>>2)&3, rblk = s&3. One glds16 = 64 lanes x 16B = 1KB LDS.
    const ushort* gbase[8];
    size_t goff[8];
    int loffv[8];
#pragma unroll
    for (int st = 0; st < 8; ++st) {
        int s = w * 8 + st;
        int comp = s >> 4;
        int kg = (s >> 2) & 3;
        int rblk = s & 3;
        int row0 = (comp < 2 ? by : bx) * 256 + rblk * 64;
        gbase[st] = (comp == 0) ? Ah : (comp == 1) ? Al : (comp == 2) ? Bh : Bl;
        goff[st] = (size_t)(row0 + l) * 1024 + kg * 8;
        loffv[st] = comp * 8192 + kg * 2048 + rblk * 512;   // ushort units
    }

    f32x4 acc[8][4];
#pragma unroll
    for (int i = 0; i < 8; ++i)
#pragma unroll
        for (int j = 0; j < 4; ++j) acc[i][j] = (f32x4){0.f, 0.f, 0.f, 0.f};

#define STAGE(bufbase_, k0_) do { \
    const int _bb = (bufbase_); const int _kk = (k0_); \
    _Pragma("unroll") \
    for (int st = 0; st < 8; ++st) \
        glds16(gbase[st] + goff[st] + _kk, &lds[_bb + loffv[st]]); \
} while (0)

    // prologue: tile 0 -> buf0, tile 1 -> buf1 (16 loads in flight)
    STAGE(0, 0);
    STAGE(32768, 32);
    asm volatile("s_waitcnt vmcnt(8)" ::: "memory");   // tile 0 resident
    __builtin_amdgcn_s_barrier();

#pragma unroll 2
    for (int t = 0; t < 32; ++t) {
        const ushort* lb = &lds[(t & 1) * 32768];

        bf16x8 fbh[4], fbl[4];
#pragma unroll
        for (int j = 0; j < 4; ++j) {
            int rb = wn * 64 + j * 16 + lr;
            fbh[j] = *(const bf16x8*)&lb[16384 + kgr * 2048 + rb * 8];
            fbl[j] = *(const bf16x8*)&lb[24576 + kgr * 2048 + rb * 8];
        }
        __builtin_amdgcn_s_setprio(1);
#pragma unroll
        for (int i = 0; i < 8; ++i) {
            int ra = wm * 128 + i * 16 + lr;
            bf16x8 fah = *(const bf16x8*)&lb[       kgr * 2048 + ra * 8];
            bf16x8 fal = *(const bf16x8*)&lb[8192 + kgr * 2048 + ra * 8];
#pragma unroll
            for (int j = 0; j < 4; ++j)
                acc[i][j] = __builtin_amdgcn_mfma_f32_16x16x32_bf16(fah, fbh[j], acc[i][j], 0, 0, 0);
#pragma unroll
            for (int j = 0; j < 4; ++j)
                acc[i][j] = __builtin_amdgcn_mfma_f32_16x16x32_bf16(fah, fbl[j], acc[i][j], 0, 0, 0);
#pragma unroll
            for (int j = 0; j < 4; ++j)
                acc[i][j] = __builtin_amdgcn_mfma_f32_16x16x32_bf16(fal, fbh[j], acc[i][j], 0, 0, 0);
        }
        __builtin_amdgcn_s_setprio(0);

        // #1: all waves done READING buf[t&1] (lgkm waits before MFMAs
        // guarantee per-wave read completion; barrier makes it block-wide)
        __builtin_amdgcn_s_barrier();

        if (t < 30) {
            STAGE((t & 1) * 32768, (t + 2) * 32);
            // outstanding: 8 (tile t+1, issued last iter) + 8 (tile t+2).
            // Wait for the OLDEST 8 only -> tile t+1 resident.
            asm volatile("s_waitcnt vmcnt(8)" ::: "memory");
        } else {
            asm volatile("s_waitcnt vmcnt(0)" ::: "memory");
        }
        // #2: tile t+1 resident for all waves
        __builtin_amdgcn_s_barrier();
    }
#undef STAGE

    // epilogue: C/D layout col = lane&15, row = (lane>>4)*4 + reg  [m89-verified]
#pragma unroll
    for (int j = 0; j < 4; ++j) {
        int col = bx * 256 + wn * 64 + j * 16 + lr;
        float bb = bias[col];
#pragma unroll
        for (int i = 0; i < 8; ++i) {
            int row0 = by * 256 + wm * 128 + i * 16 + kgr * 4;
#pragma unroll
            for (int reg = 0; reg < 4; ++reg)
                C[(size_t)(row0 + reg) * 1024 + col] = acc[i][j][reg] + bb;
        }
    }
}

// ---------------------------------------------------------------------------
// transpose (t,b,d) -> [bh][e][t]   (for coalesced FFT row loads)
// ---------------------------------------------------------------------------
__global__ __launch_bounds__(256)
void transpose_bhet(const float* __restrict__ src, float* __restrict__ dst)
{
    __shared__ float tile[64][129];
    const int tid = threadIdx.x;
    const int bh = blockIdx.x;
    const int b = bh >> 4, h = bh & 15;
    const int t0 = blockIdx.y * 128;
    const float* sp = src + (size_t)(t0 * 8 + b) * 1024 + h * 64;
#pragma unroll
    for (int i = 0; i < 8; ++i) {
        int idx = i * 256 + tid;
        int t = idx >> 4;
        int e4 = (idx & 15) * 4;
        float4 v = *(const float4*)(sp + (size_t)t * 8192 + e4);
        tile[e4 + 0][t] = v.x; tile[e4 + 1][t] = v.y; tile[e4 + 2][t] = v.z; tile[e4 + 3][t] = v.w;
    }
    __syncthreads();
    float* dp = dst + (size_t)bh * 64 * 2048 + t0;
#pragma unroll
    for (int i = 0; i < 8; ++i) {
        int idx = i * 256 + tid;
        int e = idx >> 5;
        int t4 = (idx & 31) * 4;
        float4 o;
        o.x = tile[e][t4]; o.y = tile[e][t4 + 1]; o.z = tile[e][t4 + 2]; o.w = tile[e][t4 + 3];
        *(float4*)(dp + (size_t)e * 2048 + t4) = o;
    }
}

// ---------------------------------------------------------------------------
__device__ __forceinline__ float2 cadd(float2 a, float2 b){ return make_float2(a.x+b.x, a.y+b.y); }
__device__ __forceinline__ float2 csub(float2 a, float2 b){ return make_float2(a.x-b.x, a.y-b.y); }
__device__ __forceinline__ float2 cmul(float2 a, float2 b){ return make_float2(a.x*b.x - a.y*b.y, a.x*b.y + a.y*b.x); }

// ---------------------------------------------------------------------------
// corr_fwd: grid (128 bh, 8 eg). FFT 8 packed (Q,K) rows, accumulate partial
// S[f] = sum_e Qf*conj(Kf) in registers, write to Spart[bh][eg][1025].
// Twiddle LUT: exp(-i*pi*ps/1024), ps in [0,1024) covers ALL stages.
// ---------------------------------------------------------------------------
__global__ __launch_bounds__(256)
void corr_fwd(const float* __restrict__ Qa, const float* __restrict__ Ka,
              float2* __restrict__ Spart)
{
    __shared__ float2 za[2048];
    __shared__ float2 zb[2048];
    __shared__ float2 tw[1024];
    const int tid = threadIdx.x;
    const int bh = blockIdx.x;
    const int eg = blockIdx.y;

#pragma unroll
    for (int r = 0; r < 4; ++r) {
        int u = tid + 256 * r;
        float sn, cs;
        sincospif((float)u * (1.0f / 1024.0f), &sn, &cs);
        tw[u] = make_float2(cs, -sn);
    }
    // visibility guaranteed by the __syncthreads after the first za fill

    float2 sacc[4];
#pragma unroll
    for (int r = 0; r < 4; ++r) sacc[r] = make_float2(0.f, 0.f);
    float2 sacc1024 = make_float2(0.f, 0.f);

    const float* q0 = Qa + ((size_t)bh * 64 + eg * 8) * 2048;
    const float* k0 = Ka + ((size_t)bh * 64 + eg * 8) * 2048;

    for (int e = 0; e < 8; ++e) {
        const float* qr = q0 + (size_t)e * 2048;
        const float* kr = k0 + (size_t)e * 2048;
        for (int t = tid; t < 2048; t += 256)
            za[t] = make_float2(qr[t], kr[t]);
        __syncthreads();
        float2* x = za; float2* y = zb;
#pragma unroll 1
        for (int st = 0; st < 11; ++st) {
            const int s = 1 << st;
#pragma unroll
            for (int ui = 0; ui < 4; ++ui) {
                int u = ui * 256 + tid;
                int q = u & (s - 1);
                int ps = u - q;
                float2 a  = x[u];
                float2 bb = x[u + 1024];
                float2 wv = tw[ps];
                int i1 = 2 * ps + q;
                y[i1]     = cadd(a, bb);
                y[i1 + s] = cmul(csub(a, bb), wv);
            }
            __syncthreads();
            float2* tsw = x; x = y; y = tsw;
        }
#pragma unroll
        for (int r = 0; r < 4; ++r) {
            int f = tid + 256 * r;
            float2 A  = x[f];
            float2 Bc = x[(2048 - f) & 2047];
            float Ur = A.x + Bc.x, Ui = A.y - Bc.y;
            float Vr = A.x - Bc.x, Vi = -A.y - Bc.y;
            sacc[r].x += 0.25f * (-(Ur * Vi + Ui * Vr));
            sacc[r].y += 0.25f * ( Ur * Vr - Ui * Vi );
        }
        if (tid == 0) {
            float2 A = x[1024];
            float Ur = 2.f * A.x;
            float Vi = -2.f * A.y;
            sacc1024.x += 0.25f * (-(Ur * Vi));
            sacc1024.y += 0.25f * 0.f;
        }
        __syncthreads();
    }
    float2* sp = Spart + ((size_t)bh * 8 + eg) * 1025;
#pragma unroll
    for (int r = 0; r < 4; ++r) sp[tid + 256 * r] = sacc[r];
    if (tid == 0) sp[1024] = sacc1024;
}

// ---------------------------------------------------------------------------
// corr_inv_topk: sum 8 partials, inverse FFT (conj trick), top-7 + softmax.
// ---------------------------------------------------------------------------
__global__ __launch_bounds__(256)
void corr_inv_topk(const float2* __restrict__ Spart,
                   int* __restrict__ taus, float* __restrict__ wout)
{
    __shared__ float2 za[2048];
    __shared__ float2 zb[2048];
    __shared__ float2 tw[1024];
    __shared__ float2 Sh[1025];
    __shared__ float  redv[256];
    __shared__ int    redi[256];
    __shared__ float  sc[TOPK];
    __shared__ int    si[TOPK];

    const int tid = threadIdx.x;
    const int bh = blockIdx.x;

#pragma unroll
    for (int r = 0; r < 4; ++r) {
        int u = tid + 256 * r;
        float sn, cs;
        sincospif((float)u * (1.0f / 1024.0f), &sn, &cs);
        tw[u] = make_float2(cs, -sn);
    }

    const float2* sp0 = Spart + (size_t)bh * 8 * 1025;
    for (int f = tid; f < 1025; f += 256) {
        float2 s = make_float2(0.f, 0.f);
#pragma unroll
        for (int g = 0; g < 8; ++g) {
            float2 v = sp0[(size_t)g * 1025 + f];
            s.x += v.x; s.y += v.y;
        }
        Sh[f] = s;
    }
    __syncthreads();
    for (int f = tid; f < 2048; f += 256) {
        float2 v = (f <= 1024) ? make_float2(Sh[f].x, -Sh[f].y) : Sh[2048 - f];
        za[f] = v;
    }
    __syncthreads();
    float2* xi = za; float2* yi = zb;
#pragma unroll 1
    for (int st = 0; st < 11; ++st) {
        const int s = 1 << st;
#pragma unroll
        for (int ui = 0; ui < 4; ++ui) {
            int u = ui * 256 + tid;
            int q = u & (s - 1);
            int ps = u - q;
            float2 a  = xi[u];
            float2 bb = xi[u + 1024];
            float2 wv = tw[ps];
            int i1 = 2 * ps + q;
            yi[i1]     = cadd(a, bb);
            yi[i1 + s] = cmul(csub(a, bb), wv);
        }
        __syncthreads();
        float2* tsw = xi; xi = yi; yi = tsw;
    }

    for (int k = 0; k < TOPK; ++k) {
        float bvv = -INFINITY; int bii = 0;
        for (int t = tid; t < 2048; t += 256) {
            float v = xi[t].x;
            if (v > bvv) { bvv = v; bii = t; }
        }
        redv[tid] = bvv; redi[tid] = bii;
        __syncthreads();
        for (int off = 128; off > 0; off >>= 1) {
            if (tid < off) {
                float ov = redv[tid + off]; int oi = redi[tid + off];
                if (ov > redv[tid] || (ov == redv[tid] && oi < redi[tid])) { redv[tid] = ov; redi[tid] = oi; }
            }
            __syncthreads();
        }
        if (tid == 0) { sc[k] = redv[0]; si[k] = redi[0]; xi[redi[0]].x = -INFINITY; }
        __syncthreads();
    }
    if (tid == 0) {
        const float scale = 1.0f / (2048.0f * 64.0f);
        float m = sc[0] * scale;
        float ex[TOPK]; float ssum = 0.f;
        for (int k = 0; k < TOPK; ++k) { ex[k] = expf(sc[k] * scale - m); ssum += ex[k]; }
        for (int k = 0; k < TOPK; ++k) {
            taus[bh * TOPK + k] = si[k];
            wout[bh * TOPK + k] = ex[k] / ssum;
        }
    }
}

// ---------------------------------------------------------------------------
// agg = (1/7) * sum_k w[bh][k] * V[(t+tau_k)%L, b, :]; emits (hi,lo) bf16
// directly (feeds the split-GEMM output projection).
// ---------------------------------------------------------------------------
__global__ __launch_bounds__(256)
void agg_gather(const float* __restrict__ Vp, const int* __restrict__ taus,
                const float* __restrict__ w, ushort* __restrict__ ah,
                ushort* __restrict__ al)
{
    const int tid = threadIdx.x;
    const int bh = blockIdx.x;
    const int b = bh >> 4, h = bh & 15;
    const int t0 = blockIdx.y * 256;
    __shared__ int   stau[TOPK];
    __shared__ float sw[TOPK];
    if (tid < TOPK) { stau[tid] = taus[bh * TOPK + tid]; sw[tid] = w[bh * TOPK + tid] * (1.0f / TOPK); }
    __syncthreads();
    const float* vb = Vp + (size_t)b * 1024 + h * 64;
    ushort* ahb = ah + (size_t)b * 1024 + h * 64;
    ushort* alb = al + (size_t)b * 1024 + h * 64;
#pragma unroll
    for (int i = 0; i < 16; ++i) {
        int idx = i * 256 + tid;
        int t  = t0 + (idx >> 4);
        int e4 = (idx & 15) * 4;
        float a0 = 0.f, a1 = 0.f, a2 = 0.f, a3 = 0.f;
#pragma unroll
        for (int k = 0; k < TOPK; ++k) {
            int ts = (t + stau[k]) & 2047;
            float4 v = *(const float4*)(vb + (size_t)ts * 8192 + e4);
            a0 = fmaf(sw[k], v.x, a0); a1 = fmaf(sw[k], v.y, a1);
            a2 = fmaf(sw[k], v.z, a2); a3 = fmaf(sw[k], v.w, a3);
        }
        ushort4 hh, ll;
        split1(a0, hh.x, ll.x); split1(a1, hh.y, ll.y);
        split1(a2, hh.z, ll.z); split1(a3, hh.w, ll.w);
        *(ushort4*)(ahb + (size_t)t * 8192 + e4) = hh;
        *(ushort4*)(alb + (size_t)t * 8192 + e4) = ll;
    }
}

// ---------------------------------------------------------------------------
extern "C" void kernel_launch(void* const* d_in, const int* in_sizes, int n_in,
                              void* d_out, int out_size, void* d_ws, size_t ws_size,
                              hipStream_t stream)
{
    (void)in_sizes; (void)n_in; (void)out_size; (void)ws_size;
    const float* query = (const float*)d_in[0];
    const float* key   = (const float*)d_in[1];
    const float* value = (const float*)d_in[2];
    const float* Wq = (const float*)d_in[3];
    const float* bq = (const float*)d_in[4];
    const float* Wk = (const float*)d_in[5];
    const float* bk = (const float*)d_in[6];
    const float* Wv = (const float*)d_in[7];
    const float* bv = (const float*)d_in[8];
    const float* Wo = (const float*)d_in[9];
    const float* bo = (const float*)d_in[10];
    float* out = (float*)d_out;

    const size_t NEL  = (size_t)16777216;   // 16384*1024
    const size_t HEL  = NEL / 2;            // value half
    const size_t WEL  = (size_t)1048576;    // 1024*1024
    const size_t SLOTB = (size_t)64 * 1024 * 1024;

    char* ws = (char*)d_ws;
    float*  s1 = (float*)ws;                 // fp32 proj outputs (Qp/Kp/Vp)
    char*   s2 = ws + SLOTB;                 // X(q) -> Qa -> agg hi/lo
    char*   s3 = ws + 2 * SLOTB;             // Wq -> X(k) -> Ka -> Wo
    int*    dtaus = (int*)(ws + 3 * SLOTB);
    float*  dw    = (float*)(dtaus + 128 * TOPK);

    dim3 blk(256);
    dim3 gblk(512);
    dim3 gemm_full(4, 64), gemm_half(4, 32);   // 256x256 tiles
    dim3 tr_grid(128, 16);

    // 1. Wq split -> s3
    split_f32<<<1024, blk, 0, stream>>>(Wq, (ushort*)s3, (ushort*)s3 + WEL, (int)(WEL / 4));
    // 2. query split -> s2
    split_f32<<<2048, blk, 0, stream>>>(query, (ushort*)s2, (ushort*)s2 + NEL, (int)(NEL / 4));
    // 3. Q projection -> s1
    gemm_split<<<gemm_full, gblk, 0, stream>>>((ushort*)s2, (ushort*)s2 + NEL,
                                               (ushort*)s3, (ushort*)s3 + WEL, bq, s1);
    // 4. transpose -> Qa (s2, fp32)
    transpose_bhet<<<tr_grid, blk, 0, stream>>>(s1, (float*)s2);
    // 5. Wk split -> d_out[0:4MB)
    ushort* wkh = (ushort*)d_out;
    split_f32<<<1024, blk, 0, stream>>>(Wk, wkh, wkh + WEL, (int)(WEL / 4));
    // 6. key split -> s3
    split_f32<<<2048, blk, 0, stream>>>(key, (ushort*)s3, (ushort*)s3 + NEL, (int)(NEL / 4));
    // 7. K projection -> s1
    gemm_split<<<gemm_full, gblk, 0, stream>>>((ushort*)s3, (ushort*)s3 + NEL,
                                               wkh, wkh + WEL, bk, s1);
    // 8. transpose -> Ka (s3, fp32)
    transpose_bhet<<<tr_grid, blk, 0, stream>>>(s1, (float*)s3);
    // 9. Wv split -> d_out + 32MB
    ushort* wvh = (ushort*)((char*)d_out + (size_t)32 * 1024 * 1024);
    split_f32<<<1024, blk, 0, stream>>>(Wv, wvh, wvh + WEL, (int)(WEL / 4));
    // 10-13. V projection in two M-halves (keeps value split within d_out[0:32MB))
    ushort* vsp = (ushort*)d_out;
    for (int hhalf = 0; hhalf < 2; ++hhalf) {
        split_f32<<<2048, blk, 0, stream>>>(value + hhalf * HEL, vsp, vsp + HEL, (int)(HEL / 4));
        gemm_split<<<gemm_half, gblk, 0, stream>>>(vsp, vsp + HEL, wvh, wvh + WEL,
                                                   bv, s1 + hhalf * HEL);
    }
    // 14. correlation forward (Qa=s2, Ka=s3) -> Spart in d_out
    float2* Spart = (float2*)d_out;
    corr_fwd<<<dim3(128, 8), blk, 0, stream>>>((const float*)s2, (const float*)s3, Spart);
    // 15. inverse + top-k + softmax
    corr_inv_topk<<<dim3(128), blk, 0, stream>>>(Spart, dtaus, dw);
    // 16. delayed-V aggregation -> (hi,lo) in s2
    agg_gather<<<dim3(128, 8), blk, 0, stream>>>(s1, dtaus, dw,
                                                 (ushort*)s2, (ushort*)s2 + NEL);
    // 17. Wo split -> s3
    split_f32<<<1024, blk, 0, stream>>>(Wo, (ushort*)s3, (ushort*)s3 + WEL, (int)(WEL / 4));
    // 18. output projection -> d_out
    gemm_split<<<gemm_full, gblk, 0, stream>>>((ushort*)s2, (ushort*)s2 + NEL,
                                               (ushort*)s3, (ushort*)s3 + WEL, bo, out);
}

// Round 5
// 691.323 us; speedup vs baseline: 1.3284x; 1.3284x over previous
//
#include <hip/hip_runtime.h>
#include <math.h>

#define TOPK 7
// dims (fixed by problem): L=S=2048, B=8, D=1024, H=16, E=64

typedef __attribute__((ext_vector_type(8))) short bf16x8;
typedef __attribute__((ext_vector_type(4))) float f32x4;

// ---------------------------------------------------------------------------
// async global->LDS, 16B per lane (wave-uniform LDS base + lane*16)
// ---------------------------------------------------------------------------
__device__ __forceinline__ void glds16(const ushort* g, ushort* l)
{
    __builtin_amdgcn_global_load_lds(
        (const __attribute__((address_space(1))) void*)g,
        (__attribute__((address_space(3))) void*)l, 16, 0, 0);
}

// ---------------------------------------------------------------------------
// fp32 -> (hi,lo) bf16 split, RN-even via bit ops. n4 = n/4.
// ---------------------------------------------------------------------------
__device__ __forceinline__ void split1(float x, ushort& h, ushort& lo)
{
    union U { float f; unsigned u; };
    U a; a.f = x;
    unsigned r = (a.u + 0x7FFFu + ((a.u >> 16) & 1u)) >> 16;
    h = (ushort)r;
    U b; b.u = r << 16;
    U d; d.f = x - b.f;
    unsigned r2 = (d.u + 0x7FFFu + ((d.u >> 16) & 1u)) >> 16;
    lo = (ushort)r2;
}

__global__ __launch_bounds__(256)
void split_f32(const float* __restrict__ x, ushort* __restrict__ hi,
               ushort* __restrict__ lo, int n4)
{
    for (int i = blockIdx.x * 256 + threadIdx.x; i < n4; i += gridDim.x * 256) {
        float4 v = ((const float4*)x)[i];
        ushort4 h, lw;
        split1(v.x, h.x, lw.x);
        split1(v.y, h.y, lw.y);
        split1(v.z, h.z, lw.z);
        split1(v.w, h.w, lw.w);
        ((ushort4*)hi)[i] = h;
        ((ushort4*)lo)[i] = lw;
    }
}

// ---------------------------------------------------------------------------
// split-bf16 NT GEMM: C[M,1024] = A[M,1024]*B[1024,1024]^T + bias
// A,B given as (hi,lo) bf16 pairs. C fp32.
//
// 256x256 tile, BK=32, 512 thr (8 waves as 2M x 4N; wave tile 128x64 =
// 8x4 frags of 16x16). 3 MFMAs per frag-pair: Ah*Bh + Ah*Bl + Al*Bh.
// FP accumulation order per acc element identical to previous rounds.
//
// 4-PHASE schedule (T3+T4+T5, round-5): per K-step the compute is split
// into 4 phases {Bfrags+i01, i23, i45, i67} with a barrier between each,
// and the 8 stage issues for tile t+2 are SPREAD across phases, each
// region staged only after its last reader's barrier:
//   p0: reads all of B + A rows {0-31,128-159}          -> barrier
//   p1: stage B(t+2) [B-region dead]; compute i23       -> barrier
//   p2: stage A rblk0,2 [rows 0-63,128-191 dead]; i45   -> barrier
//   p3: compute i67 -> barrier; stage A rblk1,3; vmcnt(8) -> barrier
// vmcnt(8) retires exactly the previous tile's 8 loads (T4: never 0 in
// the main loop). setprio(1) around each MFMA cluster (T5 -- the phase
// split creates the wave role-diversity that makes T4/T5 pay).
// ---------------------------------------------------------------------------
__global__ __launch_bounds__(512, 2)
void gemm_split(const ushort* __restrict__ Ah, const ushort* __restrict__ Al,
                const ushort* __restrict__ Bh, const ushort* __restrict__ Bl,
                const float* __restrict__ bias, float* __restrict__ C)
{
    __shared__ ushort lds[65536];   // 2 buffers x 64KB = 128KB
    const int tid = threadIdx.x;
    const int w = tid >> 6, l = tid & 63;

    // T1 swizzle: ord%8 == XCD (round-robin dispatch); nwg divisible by 8.
    const int ord = blockIdx.y * gridDim.x + blockIdx.x;
    const int cpx = (gridDim.x * gridDim.y) >> 3;
    const int swz = (ord & 7) * cpx + (ord >> 3);
    const int bx = swz & 3;          // gridDim.x == 4 (N tiles of 256)
    const int by = swz >> 2;         // M tile

    const int wm = w >> 2, wn = w & 3;      // 2M x 4N waves
    const int lr = l & 15, kgr = l >> 4;

    // staging descriptors: 4 B-pieces + 4 A-pieces per wave.
    // piece idx = w*4+q -> cb = w>>2 (hi/lo), kg = w&3, rblk = q.
    // One glds16 = 64 lanes x 16B = 1KB (rows rblk*64..+63, K-cols kg*8..+7).
    const ushort* gbB[4]; size_t goB[4]; int loB[4];
    const ushort* gbA[4]; size_t goA[4]; int loA[4];
#pragma unroll
    for (int q = 0; q < 4; ++q) {
        int idx = w * 4 + q;
        int cb = idx >> 4;
        int kg = (idx >> 2) & 3;
        int rblk = idx & 3;            // == q
        gbB[q] = cb ? Bl : Bh;
        goB[q] = (size_t)(bx * 256 + rblk * 64 + l) * 1024 + kg * 8;
        loB[q] = 16384 + cb * 8192 + kg * 2048 + rblk * 512;
        gbA[q] = cb ? Al : Ah;
        goA[q] = (size_t)(by * 256 + rblk * 64 + l) * 1024 + kg * 8;
        loA[q] = cb * 8192 + kg * 2048 + rblk * 512;
    }

    f32x4 acc[8][4];
#pragma unroll
    for (int i = 0; i < 8; ++i)
#pragma unroll
        for (int j = 0; j < 4; ++j) acc[i][j] = (f32x4){0.f, 0.f, 0.f, 0.f};

#define STAGE_B(bufbase_, k0_) do { \
    const int _bb = (bufbase_); const int _kk = (k0_); \
    _Pragma("unroll") \
    for (int q = 0; q < 4; ++q) \
        glds16(gbB[q] + goB[q] + _kk, &lds[_bb + loB[q]]); \
} while (0)

#define STAGE_A2(bufbase_, k0_, qa_, qb_) do { \
    const int _bb = (bufbase_); const int _kk = (k0_); \
    glds16(gbA[qa_] + goA[qa_] + _kk, &lds[_bb + loA[qa_]]); \
    glds16(gbA[qb_] + goA[qb_] + _kk, &lds[_bb + loA[qb_]]); \
} while (0)

// compute i0_, i0_+1 (24 MFMAs); uses lb, fbh, fbl, acc from scope
#define COMPUTE2(i0_) do { \
    _Pragma("unroll") \
    for (int ii = 0; ii < 2; ++ii) { \
        const int i = (i0_) + ii; \
        const int ra = wm * 128 + i * 16 + lr; \
        bf16x8 fah = *(const bf16x8*)&lb[       kgr * 2048 + ra * 8]; \
        bf16x8 fal = *(const bf16x8*)&lb[8192 + kgr * 2048 + ra * 8]; \
        __builtin_amdgcn_s_setprio(1); \
        _Pragma("unroll") \
        for (int j = 0; j < 4; ++j) \
            acc[i][j] = __builtin_amdgcn_mfma_f32_16x16x32_bf16(fah, fbh[j], acc[i][j], 0, 0, 0); \
        _Pragma("unroll") \
        for (int j = 0; j < 4; ++j) \
            acc[i][j] = __builtin_amdgcn_mfma_f32_16x16x32_bf16(fah, fbl[j], acc[i][j], 0, 0, 0); \
        _Pragma("unroll") \
        for (int j = 0; j < 4; ++j) \
            acc[i][j] = __builtin_amdgcn_mfma_f32_16x16x32_bf16(fal, fbh[j], acc[i][j], 0, 0, 0); \
        __builtin_amdgcn_s_setprio(0); \
    } \
} while (0)

    // prologue: tile 0 -> buf0, tile 1 -> buf1 (16 loads in flight/wave? no:
    // 8 per wave per tile / issue order B(4),A(4) per tile)
    STAGE_B(0, 0);       STAGE_A2(0, 0, 0, 1);       STAGE_A2(0, 0, 2, 3);
    STAGE_B(32768, 32);  STAGE_A2(32768, 32, 0, 1);  STAGE_A2(32768, 32, 2, 3);
    asm volatile("s_waitcnt vmcnt(8)" ::: "memory");   // tile 0 resident
    __builtin_amdgcn_s_barrier();

#pragma unroll 2
    for (int t = 0; t < 32; ++t) {
        const int cb = (t & 1) * 32768;
        const ushort* lb = &lds[cb];
        const bool pre = (t < 30);
        const int kn = (t + 2) * 32;

        // ---- phase 0: B-frags (8 reads) + compute i=0,1
        bf16x8 fbh[4], fbl[4];
#pragma unroll
        for (int j = 0; j < 4; ++j) {
            int rb = wn * 64 + j * 16 + lr;
            fbh[j] = *(const bf16x8*)&lb[16384 + kgr * 2048 + rb * 8];
            fbl[j] = *(const bf16x8*)&lb[24576 + kgr * 2048 + rb * 8];
        }
        COMPUTE2(0);
        __builtin_amdgcn_s_barrier();

        // ---- phase 1: stage B(t+2) into the B-region just freed; i=2,3
        if (pre) STAGE_B(cb, kn);
        COMPUTE2(2);
        __builtin_amdgcn_s_barrier();

        // ---- phase 2: stage A rblk0,2 (rows 0-63 & 128-191 dead); i=4,5
        if (pre) STAGE_A2(cb, kn, 0, 2);
        COMPUTE2(4);
        __builtin_amdgcn_s_barrier();

        // ---- phase 3: i=6,7; then stage A rblk1,3; counted vmcnt
        COMPUTE2(6);
        __builtin_amdgcn_s_barrier();
        if (pre) {
            STAGE_A2(cb, kn, 1, 3);
            // outstanding: 8 (tile t+1, spread across prev iter) + 8 (t+2).
            // Retire only the oldest 8 -> tile t+1 resident, t+2 in flight.
            asm volatile("s_waitcnt vmcnt(8)" ::: "memory");
        } else {
            asm volatile("s_waitcnt vmcnt(0)" ::: "memory");
        }
        __builtin_amdgcn_s_barrier();
    }
#undef STAGE_B
#undef STAGE_A2
#undef COMPUTE2

    // epilogue: C/D layout col = lane&15, row = (lane>>4)*4 + reg  [m89-verified]
#pragma unroll
    for (int j = 0; j < 4; ++j) {
        int col = bx * 256 + wn * 64 + j * 16 + lr;
        float bb = bias[col];
#pragma unroll
        for (int i = 0; i < 8; ++i) {
            int row0 = by * 256 + wm * 128 + i * 16 + kgr * 4;
#pragma unroll
            for (int reg = 0; reg < 4; ++reg)
                C[(size_t)(row0 + reg) * 1024 + col] = acc[i][j][reg] + bb;
        }
    }
}

// ---------------------------------------------------------------------------
// transpose (t,b,d) -> [bh][e][t]   (for coalesced FFT row loads)
// ---------------------------------------------------------------------------
__global__ __launch_bounds__(256)
void transpose_bhet(const float* __restrict__ src, float* __restrict__ dst)
{
    __shared__ float tile[64][129];
    const int tid = threadIdx.x;
    const int bh = blockIdx.x;
    const int b = bh >> 4, h = bh & 15;
    const int t0 = blockIdx.y * 128;
    const float* sp = src + (size_t)(t0 * 8 + b) * 1024 + h * 64;
#pragma unroll
    for (int i = 0; i < 8; ++i) {
        int idx = i * 256 + tid;
        int t = idx >> 4;
        int e4 = (idx & 15) * 4;
        float4 v = *(const float4*)(sp + (size_t)t * 8192 + e4);
        tile[e4 + 0][t] = v.x; tile[e4 + 1][t] = v.y; tile[e4 + 2][t] = v.z; tile[e4 + 3][t] = v.w;
    }
    __syncthreads();
    float* dp = dst + (size_t)bh * 64 * 2048 + t0;
#pragma unroll
    for (int i = 0; i < 8; ++i) {
        int idx = i * 256 + tid;
        int e = idx >> 5;
        int t4 = (idx & 31) * 4;
        float4 o;
        o.x = tile[e][t4]; o.y = tile[e][t4 + 1]; o.z = tile[e][t4 + 2]; o.w = tile[e][t4 + 3];
        *(float4*)(dp + (size_t)e * 2048 + t4) = o;
    }
}

// ---------------------------------------------------------------------------
__device__ __forceinline__ float2 cadd(float2 a, float2 b){ return make_float2(a.x+b.x, a.y+b.y); }
__device__ __forceinline__ float2 csub(float2 a, float2 b){ return make_float2(a.x-b.x, a.y-b.y); }
__device__ __forceinline__ float2 cmul(float2 a, float2 b){ return make_float2(a.x*b.x - a.y*b.y, a.x*b.y + a.y*b.x); }

// ---------------------------------------------------------------------------
// corr_fwd: grid (128 bh, 8 eg). FFT 8 packed (Q,K) rows, accumulate partial
// S[f] = sum_e Qf*conj(Kf) in registers, write to Spart[bh][eg][1025].
// Twiddle LUT: exp(-i*pi*ps/1024), ps in [0,1024) covers ALL stages.
// ---------------------------------------------------------------------------
__global__ __launch_bounds__(256)
void corr_fwd(const float* __restrict__ Qa, const float* __restrict__ Ka,
              float2* __restrict__ Spart)
{
    __shared__ float2 za[2048];
    __shared__ float2 zb[2048];
    __shared__ float2 tw[1024];
    const int tid = threadIdx.x;
    const int bh = blockIdx.x;
    const int eg = blockIdx.y;

#pragma unroll
    for (int r = 0; r < 4; ++r) {
        int u = tid + 256 * r;
        float sn, cs;
        sincospif((float)u * (1.0f / 1024.0f), &sn, &cs);
        tw[u] = make_float2(cs, -sn);
    }
    // visibility guaranteed by the __syncthreads after the first za fill

    float2 sacc[4];
#pragma unroll
    for (int r = 0; r < 4; ++r) sacc[r] = make_float2(0.f, 0.f);
    float2 sacc1024 = make_float2(0.f, 0.f);

    const float* q0 = Qa + ((size_t)bh * 64 + eg * 8) * 2048;
    const float* k0 = Ka + ((size_t)bh * 64 + eg * 8) * 2048;

    for (int e = 0; e < 8; ++e) {
        const float* qr = q0 + (size_t)e * 2048;
        const float* kr = k0 + (size_t)e * 2048;
        for (int t = tid; t < 2048; t += 256)
            za[t] = make_float2(qr[t], kr[t]);
        __syncthreads();
        float2* x = za; float2* y = zb;
#pragma unroll 1
        for (int st = 0; st < 11; ++st) {
            const int s = 1 << st;
#pragma unroll
            for (int ui = 0; ui < 4; ++ui) {
                int u = ui * 256 + tid;
                int q = u & (s - 1);
                int ps = u - q;
                float2 a  = x[u];
                float2 bb = x[u + 1024];
                float2 wv = tw[ps];
                int i1 = 2 * ps + q;
                y[i1]     = cadd(a, bb);
                y[i1 + s] = cmul(csub(a, bb), wv);
            }
            __syncthreads();
            float2* tsw = x; x = y; y = tsw;
        }
#pragma unroll
        for (int r = 0; r < 4; ++r) {
            int f = tid + 256 * r;
            float2 A  = x[f];
            float2 Bc = x[(2048 - f) & 2047];
            float Ur = A.x + Bc.x, Ui = A.y - Bc.y;
            float Vr = A.x - Bc.x, Vi = -A.y - Bc.y;
            sacc[r].x += 0.25f * (-(Ur * Vi + Ui * Vr));
            sacc[r].y += 0.25f * ( Ur * Vr - Ui * Vi );
        }
        if (tid == 0) {
            float2 A = x[1024];
            float Ur = 2.f * A.x;
            float Vi = -2.f * A.y;
            sacc1024.x += 0.25f * (-(Ur * Vi));
            sacc1024.y += 0.25f * 0.f;
        }
        __syncthreads();
    }
    float2* sp = Spart + ((size_t)bh * 8 + eg) * 1025;
#pragma unroll
    for (int r = 0; r < 4; ++r) sp[tid + 256 * r] = sacc[r];
    if (tid == 0) sp[1024] = sacc1024;
}

// ---------------------------------------------------------------------------
// corr_inv_topk: sum 8 partials, inverse FFT (conj trick), top-7 + softmax.
// ---------------------------------------------------------------------------
__global__ __launch_bounds__(256)
void corr_inv_topk(const float2* __restrict__ Spart,
                   int* __restrict__ taus, float* __restrict__ wout)
{
    __shared__ float2 za[2048];
    __shared__ float2 zb[2048];
    __shared__ float2 tw[1024];
    __shared__ float2 Sh[1025];
    __shared__ float  redv[256];
    __shared__ int    redi[256];
    __shared__ float  sc[TOPK];
    __shared__ int    si[TOPK];

    const int tid = threadIdx.x;
    const int bh = blockIdx.x;

#pragma unroll
    for (int r = 0; r < 4; ++r) {
        int u = tid + 256 * r;
        float sn, cs;
        sincospif((float)u * (1.0f / 1024.0f), &sn, &cs);
        tw[u] = make_float2(cs, -sn);
    }

    const float2* sp0 = Spart + (size_t)bh * 8 * 1025;
    for (int f = tid; f < 1025; f += 256) {
        float2 s = make_float2(0.f, 0.f);
#pragma unroll
        for (int g = 0; g < 8; ++g) {
            float2 v = sp0[(size_t)g * 1025 + f];
            s.x += v.x; s.y += v.y;
        }
        Sh[f] = s;
    }
    __syncthreads();
    for (int f = tid; f < 2048; f += 256) {
        float2 v = (f <= 1024) ? make_float2(Sh[f].x, -Sh[f].y) : Sh[2048 - f];
        za[f] = v;
    }
    __syncthreads();
    float2* xi = za; float2* yi = zb;
#pragma unroll 1
    for (int st = 0; st < 11; ++st) {
        const int s = 1 << st;
#pragma unroll
        for (int ui = 0; ui < 4; ++ui) {
            int u = ui * 256 + tid;
            int q = u & (s - 1);
            int ps = u - q;
            float2 a  = xi[u];
            float2 bb = xi[u + 1024];
            float2 wv = tw[ps];
            int i1 = 2 * ps + q;
            yi[i1]     = cadd(a, bb);
            yi[i1 + s] = cmul(csub(a, bb), wv);
        }
        __syncthreads();
        float2* tsw = xi; xi = yi; yi = tsw;
    }

    for (int k = 0; k < TOPK; ++k) {
        float bvv = -INFINITY; int bii = 0;
        for (int t = tid; t < 2048; t += 256) {
            float v = xi[t].x;
            if (v > bvv) { bvv = v; bii = t; }
        }
        redv[tid] = bvv; redi[tid] = bii;
        __syncthreads();
        for (int off = 128; off > 0; off >>= 1) {
            if (tid < off) {
                float ov = redv[tid + off]; int oi = redi[tid + off];
                if (ov > redv[tid] || (ov == redv[tid] && oi < redi[tid])) { redv[tid] = ov; redi[tid] = oi; }
            }
            __syncthreads();
        }
        if (tid == 0) { sc[k] = redv[0]; si[k] = redi[0]; xi[redi[0]].x = -INFINITY; }
        __syncthreads();
    }
    if (tid == 0) {
        const float scale = 1.0f / (2048.0f * 64.0f);
        float m = sc[0] * scale;
        float ex[TOPK]; float ssum = 0.f;
        for (int k = 0; k < TOPK; ++k) { ex[k] = expf(sc[k] * scale - m); ssum += ex[k]; }
        for (int k = 0; k < TOPK; ++k) {
            taus[bh * TOPK + k] = si[k];
            wout[bh * TOPK + k] = ex[k] / ssum;
        }
    }
}

// ---------------------------------------------------------------------------
// agg = (1/7) * sum_k w[bh][k] * V[(t+tau_k)%L, b, :]; emits (hi,lo) bf16
// directly (feeds the split-GEMM output projection).
// ---------------------------------------------------------------------------
__global__ __launch_bounds__(256)
void agg_gather(const float* __restrict__ Vp, const int* __restrict__ taus,
                const float* __restrict__ w, ushort* __restrict__ ah,
                ushort* __restrict__ al)
{
    const int tid = threadIdx.x;
    const int bh = blockIdx.x;
    const int b = bh >> 4, h = bh & 15;
    const int t0 = blockIdx.y * 256;
    __shared__ int   stau[TOPK];
    __shared__ float sw[TOPK];
    if (tid < TOPK) { stau[tid] = taus[bh * TOPK + tid]; sw[tid] = w[bh * TOPK + tid] * (1.0f / TOPK); }
    __syncthreads();
    const float* vb = Vp + (size_t)b * 1024 + h * 64;
    ushort* ahb = ah + (size_t)b * 1024 + h * 64;
    ushort* alb = al + (size_t)b * 1024 + h * 64;
#pragma unroll
    for (int i = 0; i < 16; ++i) {
        int idx = i * 256 + tid;
        int t  = t0 + (idx >> 4);
        int e4 = (idx & 15) * 4;
        float a0 = 0.f, a1 = 0.f, a2 = 0.f, a3 = 0.f;
#pragma unroll
        for (int k = 0; k < TOPK; ++k) {
            int ts = (t + stau[k]) & 2047;
            float4 v = *(const float4*)(vb + (size_t)ts * 8192 + e4);
            a0 = fmaf(sw[k], v.x, a0); a1 = fmaf(sw[k], v.y, a1);
            a2 = fmaf(sw[k], v.z, a2); a3 = fmaf(sw[k], v.w, a3);
        }
        ushort4 hh, ll;
        split1(a0, hh.x, ll.x); split1(a1, hh.y, ll.y);
        split1(a2, hh.z, ll.z); split1(a3, hh.w, ll.w);
        *(ushort4*)(ahb + (size_t)t * 8192 + e4) = hh;
        *(ushort4*)(alb + (size_t)t * 8192 + e4) = ll;
    }
}

// ---------------------------------------------------------------------------
extern "C" void kernel_launch(void* const* d_in, const int* in_sizes, int n_in,
                              void* d_out, int out_size, void* d_ws, size_t ws_size,
                              hipStream_t stream)
{
    (void)in_sizes; (void)n_in; (void)out_size;
    const float* query = (const float*)d_in[0];
    const float* key   = (const float*)d_in[1];
    const float* value = (const float*)d_in[2];
    const float* Wq = (const float*)d_in[3];
    const float* bq = (const float*)d_in[4];
    const float* Wk = (const float*)d_in[5];
    const float* bk = (const float*)d_in[6];
    const float* Wv = (const float*)d_in[7];
    const float* bv = (const float*)d_in[8];
    const float* Wo = (const float*)d_in[9];
    const float* bo = (const float*)d_in[10];
    float* out = (float*)d_out;

    const size_t NEL  = (size_t)16777216;   // 16384*1024
    const size_t HEL  = NEL / 2;            // value half
    const size_t WEL  = (size_t)1048576;    // 1024*1024
    const size_t SLOTB = (size_t)64 * 1024 * 1024;

    char* ws = (char*)d_ws;
    float*  s1 = (float*)ws;                 // fp32 proj outputs (Qp/Kp/Vp)
    char*   s2 = ws + SLOTB;                 // X(q) -> Qa -> agg hi/lo
    char*   s3 = ws + 2 * SLOTB;             // Wq -> X(k) -> Ka -> Wo
    int*    dtaus = (int*)(ws + 3 * SLOTB);
    float*  dw    = (float*)(dtaus + 128 * TOPK);
    // Wv split home: workspace tail if available (enables a FULL-GRID single
    // V gemm: value split then occupies all 64MB of d_out). Fallback: the old
    // two-half path with Wv at d_out+32MB.
    const bool big_ws = ws_size >= 3 * SLOTB + (size_t)16 * 1024 * 1024;

    dim3 blk(256);
    dim3 gblk(512);
    dim3 gemm_full(4, 64), gemm_half(4, 32);   // 256x256 tiles
    dim3 tr_grid(128, 16);

    // 1. Wq split -> s3
    split_f32<<<1024, blk, 0, stream>>>(Wq, (ushort*)s3, (ushort*)s3 + WEL, (int)(WEL / 4));
    // 2. query split -> s2
    split_f32<<<2048, blk, 0, stream>>>(query, (ushort*)s2, (ushort*)s2 + NEL, (int)(NEL / 4));
    // 3. Q projection -> s1
    gemm_split<<<gemm_full, gblk, 0, stream>>>((ushort*)s2, (ushort*)s2 + NEL,
                                               (ushort*)s3, (ushort*)s3 + WEL, bq, s1);
    // 4. transpose -> Qa (s2, fp32)
    transpose_bhet<<<tr_grid, blk, 0, stream>>>(s1, (float*)s2);
    // 5. Wk split -> d_out[0:4MB)
    ushort* wkh = (ushort*)d_out;
    split_f32<<<1024, blk, 0, stream>>>(Wk, wkh, wkh + WEL, (int)(WEL / 4));
    // 6. key split -> s3
    split_f32<<<2048, blk, 0, stream>>>(key, (ushort*)s3, (ushort*)s3 + NEL, (int)(NEL / 4));
    // 7. K projection -> s1
    gemm_split<<<gemm_full, gblk, 0, stream>>>((ushort*)s3, (ushort*)s3 + NEL,
                                               wkh, wkh + WEL, bk, s1);
    // 8. transpose -> Ka (s3, fp32)
    transpose_bhet<<<tr_grid, blk, 0, stream>>>(s1, (float*)s3);

    // 9-13. V projection
    if (big_ws) {
        ushort* wvh = (ushort*)(ws + 3 * SLOTB + (size_t)8 * 1024 * 1024);
        split_f32<<<1024, blk, 0, stream>>>(Wv, wvh, wvh + WEL, (int)(WEL / 4));
        ushort* vsp = (ushort*)d_out;        // hi [0:32MB), lo [32:64MB)
        split_f32<<<2048, blk, 0, stream>>>(value, vsp, vsp + NEL, (int)(NEL / 4));
        gemm_split<<<gemm_full, gblk, 0, stream>>>(vsp, vsp + NEL, wvh, wvh + WEL,
                                                   bv, s1);
    } else {
        ushort* wvh = (ushort*)((char*)d_out + (size_t)32 * 1024 * 1024);
        split_f32<<<1024, blk, 0, stream>>>(Wv, wvh, wvh + WEL, (int)(WEL / 4));
        ushort* vsp = (ushort*)d_out;
        for (int hhalf = 0; hhalf < 2; ++hhalf) {
            split_f32<<<2048, blk, 0, stream>>>(value + hhalf * HEL, vsp, vsp + HEL, (int)(HEL / 4));
            gemm_split<<<gemm_half, gblk, 0, stream>>>(vsp, vsp + HEL, wvh, wvh + WEL,
                                                       bv, s1 + hhalf * HEL);
        }
    }

    // 14. correlation forward (Qa=s2, Ka=s3) -> Spart in d_out
    float2* Spart = (float2*)d_out;
    corr_fwd<<<dim3(128, 8), blk, 0, stream>>>((const float*)s2, (const float*)s3, Spart);
    // 15. inverse + top-k + softmax
    corr_inv_topk<<<dim3(128), blk, 0, stream>>>(Spart, dtaus, dw);
    // 16. delayed-V aggregation -> (hi,lo) in s2
    agg_gather<<<dim3(128, 8), blk, 0, stream>>>(s1, dtaus, dw,
                                                 (ushort*)s2, (ushort*)s2 + NEL);
    // 17. Wo split -> s3
    split_f32<<<1024, blk, 0, stream>>>(Wo, (ushort*)s3, (ushort*)s3 + WEL, (int)(WEL / 4));
    // 18. output projection -> d_out
    gemm_split<<<gemm_full, gblk, 0, stream>>>((ushort*)s2, (ushort*)s2 + NEL,
                                               (ushort*)s3, (ushort*)s3 + WEL, bo, out);
}

// Round 6
// 626.146 us; speedup vs baseline: 1.4666x; 1.1041x over previous
//
#include <hip/hip_runtime.h>
#include <math.h>

#define TOPK 7
// dims (fixed by problem): L=S=2048, B=8, D=1024, H=16, E=64

typedef __attribute__((ext_vector_type(8))) short bf16x8;
typedef __attribute__((ext_vector_type(4))) float f32x4;

// ---------------------------------------------------------------------------
// async global->LDS, 16B per lane (wave-uniform LDS base + lane*16)
// ---------------------------------------------------------------------------
__device__ __forceinline__ void glds16(const ushort* g, ushort* l)
{
    __builtin_amdgcn_global_load_lds(
        (const __attribute__((address_space(1))) void*)g,
        (__attribute__((address_space(3))) void*)l, 16, 0, 0);
}

// ---------------------------------------------------------------------------
// fp32 -> (hi,lo) bf16 split, RN-even via bit ops. n4 = n/4.
// ---------------------------------------------------------------------------
__device__ __forceinline__ void split1(float x, ushort& h, ushort& lo)
{
    union U { float f; unsigned u; };
    U a; a.f = x;
    unsigned r = (a.u + 0x7FFFu + ((a.u >> 16) & 1u)) >> 16;
    h = (ushort)r;
    U b; b.u = r << 16;
    U d; d.f = x - b.f;
    unsigned r2 = (d.u + 0x7FFFu + ((d.u >> 16) & 1u)) >> 16;
    lo = (ushort)r2;
}

__global__ __launch_bounds__(256)
void split_f32(const float* __restrict__ x, ushort* __restrict__ hi,
               ushort* __restrict__ lo, int n4)
{
    for (int i = blockIdx.x * 256 + threadIdx.x; i < n4; i += gridDim.x * 256) {
        float4 v = ((const float4*)x)[i];
        ushort4 h, lw;
        split1(v.x, h.x, lw.x);
        split1(v.y, h.y, lw.y);
        split1(v.z, h.z, lw.z);
        split1(v.w, h.w, lw.w);
        ((ushort4*)hi)[i] = h;
        ((ushort4*)lo)[i] = lw;
    }
}

// ---------------------------------------------------------------------------
// split-bf16 NT GEMM: C[M,1024] = A[M,1024]*B[1024,1024]^T + bias
// 256x256 tile, BK=32, 512 thr, 4-phase T3+T4+T5 schedule (see round 5).
// ---------------------------------------------------------------------------
__global__ __launch_bounds__(512, 2)
void gemm_split(const ushort* __restrict__ Ah, const ushort* __restrict__ Al,
                const ushort* __restrict__ Bh, const ushort* __restrict__ Bl,
                const float* __restrict__ bias, float* __restrict__ C)
{
    __shared__ ushort lds[65536];   // 2 buffers x 64KB = 128KB
    const int tid = threadIdx.x;
    const int w = tid >> 6, l = tid & 63;

    // T1 swizzle: ord%8 == XCD (round-robin dispatch); nwg divisible by 8.
    const int ord = blockIdx.y * gridDim.x + blockIdx.x;
    const int cpx = (gridDim.x * gridDim.y) >> 3;
    const int swzb = (ord & 7) * cpx + (ord >> 3);
    const int bx = swzb & 3;         // gridDim.x == 4 (N tiles of 256)
    const int by = swzb >> 2;        // M tile

    const int wm = w >> 2, wn = w & 3;      // 2M x 4N waves
    const int lr = l & 15, kgr = l >> 4;

    // staging descriptors: 4 B-pieces + 4 A-pieces per wave.
    const ushort* gbB[4]; size_t goB[4]; int loB[4];
    const ushort* gbA[4]; size_t goA[4]; int loA[4];
#pragma unroll
    for (int q = 0; q < 4; ++q) {
        int idx = w * 4 + q;
        int cb = idx >> 4;
        int kg = (idx >> 2) & 3;
        int rblk = idx & 3;            // == q
        gbB[q] = cb ? Bl : Bh;
        goB[q] = (size_t)(bx * 256 + rblk * 64 + l) * 1024 + kg * 8;
        loB[q] = 16384 + cb * 8192 + kg * 2048 + rblk * 512;
        gbA[q] = cb ? Al : Ah;
        goA[q] = (size_t)(by * 256 + rblk * 64 + l) * 1024 + kg * 8;
        loA[q] = cb * 8192 + kg * 2048 + rblk * 512;
    }

    f32x4 acc[8][4];
#pragma unroll
    for (int i = 0; i < 8; ++i)
#pragma unroll
        for (int j = 0; j < 4; ++j) acc[i][j] = (f32x4){0.f, 0.f, 0.f, 0.f};

#define STAGE_B(bufbase_, k0_) do { \
    const int _bb = (bufbase_); const int _kk = (k0_); \
    _Pragma("unroll") \
    for (int q = 0; q < 4; ++q) \
        glds16(gbB[q] + goB[q] + _kk, &lds[_bb + loB[q]]); \
} while (0)

#define STAGE_A2(bufbase_, k0_, qa_, qb_) do { \
    const int _bb = (bufbase_); const int _kk = (k0_); \
    glds16(gbA[qa_] + goA[qa_] + _kk, &lds[_bb + loA[qa_]]); \
    glds16(gbA[qb_] + goA[qb_] + _kk, &lds[_bb + loA[qb_]]); \
} while (0)

#define COMPUTE2(i0_) do { \
    _Pragma("unroll") \
    for (int ii = 0; ii < 2; ++ii) { \
        const int i = (i0_) + ii; \
        const int ra = wm * 128 + i * 16 + lr; \
        bf16x8 fah = *(const bf16x8*)&lb[       kgr * 2048 + ra * 8]; \
        bf16x8 fal = *(const bf16x8*)&lb[8192 + kgr * 2048 + ra * 8]; \
        __builtin_amdgcn_s_setprio(1); \
        _Pragma("unroll") \
        for (int j = 0; j < 4; ++j) \
            acc[i][j] = __builtin_amdgcn_mfma_f32_16x16x32_bf16(fah, fbh[j], acc[i][j], 0, 0, 0); \
        _Pragma("unroll") \
        for (int j = 0; j < 4; ++j) \
            acc[i][j] = __builtin_amdgcn_mfma_f32_16x16x32_bf16(fah, fbl[j], acc[i][j], 0, 0, 0); \
        _Pragma("unroll") \
        for (int j = 0; j < 4; ++j) \
            acc[i][j] = __builtin_amdgcn_mfma_f32_16x16x32_bf16(fal, fbh[j], acc[i][j], 0, 0, 0); \
        __builtin_amdgcn_s_setprio(0); \
    } \
} while (0)

    // prologue: tile 0 -> buf0, tile 1 -> buf1
    STAGE_B(0, 0);       STAGE_A2(0, 0, 0, 1);       STAGE_A2(0, 0, 2, 3);
    STAGE_B(32768, 32);  STAGE_A2(32768, 32, 0, 1);  STAGE_A2(32768, 32, 2, 3);
    asm volatile("s_waitcnt vmcnt(8)" ::: "memory");   // tile 0 resident
    __builtin_amdgcn_s_barrier();

#pragma unroll 2
    for (int t = 0; t < 32; ++t) {
        const int cb = (t & 1) * 32768;
        const ushort* lb = &lds[cb];
        const bool pre = (t < 30);
        const int kn = (t + 2) * 32;

        // ---- phase 0: B-frags (8 reads) + compute i=0,1
        bf16x8 fbh[4], fbl[4];
#pragma unroll
        for (int j = 0; j < 4; ++j) {
            int rb = wn * 64 + j * 16 + lr;
            fbh[j] = *(const bf16x8*)&lb[16384 + kgr * 2048 + rb * 8];
            fbl[j] = *(const bf16x8*)&lb[24576 + kgr * 2048 + rb * 8];
        }
        COMPUTE2(0);
        __builtin_amdgcn_s_barrier();

        // ---- phase 1: stage B(t+2) into the freed B-region; i=2,3
        if (pre) STAGE_B(cb, kn);
        COMPUTE2(2);
        __builtin_amdgcn_s_barrier();

        // ---- phase 2: stage A rblk0,2; i=4,5
        if (pre) STAGE_A2(cb, kn, 0, 2);
        COMPUTE2(4);
        __builtin_amdgcn_s_barrier();

        // ---- phase 3: i=6,7; then stage A rblk1,3; counted vmcnt
        COMPUTE2(6);
        __builtin_amdgcn_s_barrier();
        if (pre) {
            STAGE_A2(cb, kn, 1, 3);
            asm volatile("s_waitcnt vmcnt(8)" ::: "memory");
        } else {
            asm volatile("s_waitcnt vmcnt(0)" ::: "memory");
        }
        __builtin_amdgcn_s_barrier();
    }
#undef STAGE_B
#undef STAGE_A2
#undef COMPUTE2

    // epilogue: C/D layout col = lane&15, row = (lane>>4)*4 + reg  [m89-verified]
#pragma unroll
    for (int j = 0; j < 4; ++j) {
        int col = bx * 256 + wn * 64 + j * 16 + lr;
        float bb = bias[col];
#pragma unroll
        for (int i = 0; i < 8; ++i) {
            int row0 = by * 256 + wm * 128 + i * 16 + kgr * 4;
#pragma unroll
            for (int reg = 0; reg < 4; ++reg)
                C[(size_t)(row0 + reg) * 1024 + col] = acc[i][j][reg] + bb;
        }
    }
}

// ---------------------------------------------------------------------------
// transpose (t,b,d) -> [bh][e][t]   (for coalesced FFT row loads)
// ---------------------------------------------------------------------------
__global__ __launch_bounds__(256)
void transpose_bhet(const float* __restrict__ src, float* __restrict__ dst)
{
    __shared__ float tile[64][129];
    const int tid = threadIdx.x;
    const int bh = blockIdx.x;
    const int b = bh >> 4, h = bh & 15;
    const int t0 = blockIdx.y * 128;
    const float* sp = src + (size_t)(t0 * 8 + b) * 1024 + h * 64;
#pragma unroll
    for (int i = 0; i < 8; ++i) {
        int idx = i * 256 + tid;
        int t = idx >> 4;
        int e4 = (idx & 15) * 4;
        float4 v = *(const float4*)(sp + (size_t)t * 8192 + e4);
        tile[e4 + 0][t] = v.x; tile[e4 + 1][t] = v.y; tile[e4 + 2][t] = v.z; tile[e4 + 3][t] = v.w;
    }
    __syncthreads();
    float* dp = dst + (size_t)bh * 64 * 2048 + t0;
#pragma unroll
    for (int i = 0; i < 8; ++i) {
        int idx = i * 256 + tid;
        int e = idx >> 5;
        int t4 = (idx & 31) * 4;
        float4 o;
        o.x = tile[e][t4]; o.y = tile[e][t4 + 1]; o.z = tile[e][t4 + 2]; o.w = tile[e][t4 + 3];
        *(float4*)(dp + (size_t)e * 2048 + t4) = o;
    }
}

// ---------------------------------------------------------------------------
__device__ __forceinline__ float2 cadd(float2 a, float2 b){ return make_float2(a.x+b.x, a.y+b.y); }
__device__ __forceinline__ float2 csub(float2 a, float2 b){ return make_float2(a.x-b.x, a.y-b.y); }
__device__ __forceinline__ float2 cmul(float2 a, float2 b){ return make_float2(a.x*b.x - a.y*b.y, a.x*b.y + a.y*b.x); }

// ---------------------------------------------------------------------------
// XOR bank-swizzle for the FFT LDS buffers (bijective on [0,2048)):
// spreads the radix-4 stride-4s scatter writes across all 32 banks.
// ALL accesses to za/zb go through swz().
// ---------------------------------------------------------------------------
__device__ __forceinline__ int swz(int i) { return i ^ ((i >> 4) & 15); }

// ---------------------------------------------------------------------------
// In-LDS 2048-pt complex FFT: 5 radix-4 Stockham stages + 1 twiddle-free
// radix-2 stage = 6 LDS passes (vs 11 radix-2). Derived by EXACT algebraic
// composition of the verified radix-2 stage pairs (s,2s) -> identical
// output ordering; only FP rounding order differs.
//   o0 = (a+c)+(b+d)
//   o1 = [(a-c) - i(b-d)] * W^ps          W = exp(-2*pi*i/2048) (tw LUT)
//   o2 = [(a+c)-(b+d)] * W^2ps
//   o3 = [(a-c) + i(b-d)] * W^3ps         (W^3ps = w1*w2, 1ulp)
// Caller fills x via swz() and __syncthreads first. Returns result buffer.
// ---------------------------------------------------------------------------
__device__ float2* fft2048(float2* x, float2* y, const float2* tw, int tid)
{
#pragma unroll 1
    for (int st = 0; st < 5; ++st) {
        const int s = 1 << (2 * st);   // 1,4,16,64,256
#pragma unroll
        for (int ui = 0; ui < 2; ++ui) {
            const int u = ui * 256 + tid;
            const int q = u & (s - 1);
            const int ps = u - q;
            float2 a = x[swz(u)],        b = x[swz(u + 512)];
            float2 c = x[swz(u + 1024)], d = x[swz(u + 1536)];
            float2 t0 = cadd(a, c), t1 = csub(a, c);
            float2 t2 = cadd(b, d), tb = csub(b, d);
            float2 t3 = make_float2(tb.y, -tb.x);     // -i*(b-d)
            float2 w1 = tw[ps];
            float2 w2 = tw[2 * ps];
            float2 w3 = cmul(w1, w2);
            const int o = 4 * ps + q;
            y[swz(o)]         = cadd(t0, t2);
            y[swz(o + s)]     = cmul(cadd(t1, t3), w1);
            y[swz(o + 2 * s)] = cmul(csub(t0, t2), w2);
            y[swz(o + 3 * s)] = cmul(csub(t1, t3), w3);
        }
        __syncthreads();
        float2* tsw = x; x = y; y = tsw;
    }
    // final radix-2 stage (s=1024): twiddle-free
#pragma unroll
    for (int ui = 0; ui < 4; ++ui) {
        const int u = ui * 256 + tid;
        float2 a = x[swz(u)], b = x[swz(u + 1024)];
        y[swz(u)]        = cadd(a, b);
        y[swz(u + 1024)] = csub(a, b);
    }
    __syncthreads();
    return y;
}

// ---------------------------------------------------------------------------
// corr_fwd: grid (128 bh, 8 eg). FFT 8 packed (Q,K) rows, accumulate partial
// S[f] = sum_e Qf*conj(Kf) in registers, write to Spart[bh][eg][1025].
// ---------------------------------------------------------------------------
__global__ __launch_bounds__(256)
void corr_fwd(const float* __restrict__ Qa, const float* __restrict__ Ka,
              float2* __restrict__ Spart)
{
    __shared__ float2 za[2048];
    __shared__ float2 zb[2048];
    __shared__ float2 tw[1024];
    const int tid = threadIdx.x;
    const int bh = blockIdx.x;
    const int eg = blockIdx.y;

#pragma unroll
    for (int r = 0; r < 4; ++r) {
        int u = tid + 256 * r;
        float sn, cs;
        sincospif((float)u * (1.0f / 1024.0f), &sn, &cs);
        tw[u] = make_float2(cs, -sn);
    }
    // visibility guaranteed by the __syncthreads after the first za fill

    float2 sacc[4];
#pragma unroll
    for (int r = 0; r < 4; ++r) sacc[r] = make_float2(0.f, 0.f);
    float2 sacc1024 = make_float2(0.f, 0.f);

    const float* q0 = Qa + ((size_t)bh * 64 + eg * 8) * 2048;
    const float* k0 = Ka + ((size_t)bh * 64 + eg * 8) * 2048;

    for (int e = 0; e < 8; ++e) {
        const float* qr = q0 + (size_t)e * 2048;
        const float* kr = k0 + (size_t)e * 2048;
        for (int t = tid; t < 2048; t += 256)
            za[swz(t)] = make_float2(qr[t], kr[t]);
        __syncthreads();

        float2* res = fft2048(za, zb, tw, tid);

#pragma unroll
        for (int r = 0; r < 4; ++r) {
            int f = tid + 256 * r;
            float2 A  = res[swz(f)];
            float2 Bc = res[swz((2048 - f) & 2047)];
            float Ur = A.x + Bc.x, Ui = A.y - Bc.y;
            float Vr = A.x - Bc.x, Vi = -A.y - Bc.y;
            sacc[r].x += 0.25f * (-(Ur * Vi + Ui * Vr));
            sacc[r].y += 0.25f * ( Ur * Vr - Ui * Vi );
        }
        if (tid == 0) {
            float2 A = res[swz(1024)];
            float Ur = 2.f * A.x;
            float Vi = -2.f * A.y;
            sacc1024.x += 0.25f * (-(Ur * Vi));
            sacc1024.y += 0.25f * 0.f;
        }
        __syncthreads();
    }
    float2* sp = Spart + ((size_t)bh * 8 + eg) * 1025;
#pragma unroll
    for (int r = 0; r < 4; ++r) sp[tid + 256 * r] = sacc[r];
    if (tid == 0) sp[1024] = sacc1024;
}

// ---------------------------------------------------------------------------
// corr_inv_topk: sum 8 partials, inverse FFT (conj trick), top-7 + softmax.
// ---------------------------------------------------------------------------
__global__ __launch_bounds__(256)
void corr_inv_topk(const float2* __restrict__ Spart,
                   int* __restrict__ taus, float* __restrict__ wout)
{
    __shared__ float2 za[2048];
    __shared__ float2 zb[2048];
    __shared__ float2 tw[1024];
    __shared__ float2 Sh[1025];
    __shared__ float  redv[256];
    __shared__ int    redi[256];
    __shared__ float  sc[TOPK];
    __shared__ int    si[TOPK];

    const int tid = threadIdx.x;
    const int bh = blockIdx.x;

#pragma unroll
    for (int r = 0; r < 4; ++r) {
        int u = tid + 256 * r;
        float sn, cs;
        sincospif((float)u * (1.0f / 1024.0f), &sn, &cs);
        tw[u] = make_float2(cs, -sn);
    }

    const float2* sp0 = Spart + (size_t)bh * 8 * 1025;
    for (int f = tid; f < 1025; f += 256) {
        float2 s = make_float2(0.f, 0.f);
#pragma unroll
        for (int g = 0; g < 8; ++g) {
            float2 v = sp0[(size_t)g * 1025 + f];
            s.x += v.x; s.y += v.y;
        }
        Sh[f] = s;
    }
    __syncthreads();
    for (int f = tid; f < 2048; f += 256) {
        float2 v = (f <= 1024) ? make_float2(Sh[f].x, -Sh[f].y) : Sh[2048 - f];
        za[swz(f)] = v;
    }
    __syncthreads();

    float2* res = fft2048(za, zb, tw, tid);

    for (int k = 0; k < TOPK; ++k) {
        float bvv = -INFINITY; int bii = 0;
        for (int t = tid; t < 2048; t += 256) {
            float v = res[swz(t)].x;
            if (v > bvv) { bvv = v; bii = t; }
        }
        redv[tid] = bvv; redi[tid] = bii;
        __syncthreads();
        for (int off = 128; off > 0; off >>= 1) {
            if (tid < off) {
                float ov = redv[tid + off]; int oi = redi[tid + off];
                if (ov > redv[tid] || (ov == redv[tid] && oi < redi[tid])) { redv[tid] = ov; redi[tid] = oi; }
            }
            __syncthreads();
        }
        if (tid == 0) { sc[k] = redv[0]; si[k] = redi[0]; res[swz(redi[0])].x = -INFINITY; }
        __syncthreads();
    }
    if (tid == 0) {
        const float scale = 1.0f / (2048.0f * 64.0f);
        float m = sc[0] * scale;
        float ex[TOPK]; float ssum = 0.f;
        for (int k = 0; k < TOPK; ++k) { ex[k] = expf(sc[k] * scale - m); ssum += ex[k]; }
        for (int k = 0; k < TOPK; ++k) {
            taus[bh * TOPK + k] = si[k];
            wout[bh * TOPK + k] = ex[k] / ssum;
        }
    }
}

// ---------------------------------------------------------------------------
// agg = (1/7) * sum_k w[bh][k] * V[(t+tau_k)%L, b, :]; emits (hi,lo) bf16
// directly (feeds the split-GEMM output projection).
// ---------------------------------------------------------------------------
__global__ __launch_bounds__(256)
void agg_gather(const float* __restrict__ Vp, const int* __restrict__ taus,
                const float* __restrict__ w, ushort* __restrict__ ah,
                ushort* __restrict__ al)
{
    const int tid = threadIdx.x;
    const int bh = blockIdx.x;
    const int b = bh >> 4, h = bh & 15;
    const int t0 = blockIdx.y * 256;
    __shared__ int   stau[TOPK];
    __shared__ float sw[TOPK];
    if (tid < TOPK) { stau[tid] = taus[bh * TOPK + tid]; sw[tid] = w[bh * TOPK + tid] * (1.0f / TOPK); }
    __syncthreads();
    const float* vb = Vp + (size_t)b * 1024 + h * 64;
    ushort* ahb = ah + (size_t)b * 1024 + h * 64;
    ushort* alb = al + (size_t)b * 1024 + h * 64;
#pragma unroll
    for (int i = 0; i < 16; ++i) {
        int idx = i * 256 + tid;
        int t  = t0 + (idx >> 4);
        int e4 = (idx & 15) * 4;
        float a0 = 0.f, a1 = 0.f, a2 = 0.f, a3 = 0.f;
#pragma unroll
        for (int k = 0; k < TOPK; ++k) {
            int ts = (t + stau[k]) & 2047;
            float4 v = *(const float4*)(vb + (size_t)ts * 8192 + e4);
            a0 = fmaf(sw[k], v.x, a0); a1 = fmaf(sw[k], v.y, a1);
            a2 = fmaf(sw[k], v.z, a2); a3 = fmaf(sw[k], v.w, a3);
        }
        ushort4 hh, ll;
        split1(a0, hh.x, ll.x); split1(a1, hh.y, ll.y);
        split1(a2, hh.z, ll.z); split1(a3, hh.w, ll.w);
        *(ushort4*)(ahb + (size_t)t * 8192 + e4) = hh;
        *(ushort4*)(alb + (size_t)t * 8192 + e4) = ll;
    }
}

// ---------------------------------------------------------------------------
extern "C" void kernel_launch(void* const* d_in, const int* in_sizes, int n_in,
                              void* d_out, int out_size, void* d_ws, size_t ws_size,
                              hipStream_t stream)
{
    (void)in_sizes; (void)n_in; (void)out_size;
    const float* query = (const float*)d_in[0];
    const float* key   = (const float*)d_in[1];
    const float* value = (const float*)d_in[2];
    const float* Wq = (const float*)d_in[3];
    const float* bq = (const float*)d_in[4];
    const float* Wk = (const float*)d_in[5];
    const float* bk = (const float*)d_in[6];
    const float* Wv = (const float*)d_in[7];
    const float* bv = (const float*)d_in[8];
    const float* Wo = (const float*)d_in[9];
    const float* bo = (const float*)d_in[10];
    float* out = (float*)d_out;

    const size_t NEL  = (size_t)16777216;   // 16384*1024
    const size_t HEL  = NEL / 2;            // value half
    const size_t WEL  = (size_t)1048576;    // 1024*1024
    const size_t SLOTB = (size_t)64 * 1024 * 1024;

    char* ws = (char*)d_ws;
    float*  s1 = (float*)ws;                 // fp32 proj outputs (Qp/Kp/Vp)
    char*   s2 = ws + SLOTB;                 // X(q) -> Qa -> agg hi/lo
    char*   s3 = ws + 2 * SLOTB;             // Wq -> X(k) -> Ka -> Wo
    int*    dtaus = (int*)(ws + 3 * SLOTB);
    float*  dw    = (float*)(dtaus + 128 * TOPK);
    const bool big_ws = ws_size >= 3 * SLOTB + (size_t)16 * 1024 * 1024;

    dim3 blk(256);
    dim3 gblk(512);
    dim3 gemm_full(4, 64), gemm_half(4, 32);   // 256x256 tiles
    dim3 tr_grid(128, 16);

    // 1. Wq split -> s3
    split_f32<<<1024, blk, 0, stream>>>(Wq, (ushort*)s3, (ushort*)s3 + WEL, (int)(WEL / 4));
    // 2. query split -> s2
    split_f32<<<2048, blk, 0, stream>>>(query, (ushort*)s2, (ushort*)s2 + NEL, (int)(NEL / 4));
    // 3. Q projection -> s1
    gemm_split<<<gemm_full, gblk, 0, stream>>>((ushort*)s2, (ushort*)s2 + NEL,
                                               (ushort*)s3, (ushort*)s3 + WEL, bq, s1);
    // 4. transpose -> Qa (s2, fp32)
    transpose_bhet<<<tr_grid, blk, 0, stream>>>(s1, (float*)s2);
    // 5. Wk split -> d_out[0:4MB)
    ushort* wkh = (ushort*)d_out;
    split_f32<<<1024, blk, 0, stream>>>(Wk, wkh, wkh + WEL, (int)(WEL / 4));
    // 6. key split -> s3
    split_f32<<<2048, blk, 0, stream>>>(key, (ushort*)s3, (ushort*)s3 + NEL, (int)(NEL / 4));
    // 7. K projection -> s1
    gemm_split<<<gemm_full, gblk, 0, stream>>>((ushort*)s3, (ushort*)s3 + NEL,
                                               wkh, wkh + WEL, bk, s1);
    // 8. transpose -> Ka (s3, fp32)
    transpose_bhet<<<tr_grid, blk, 0, stream>>>(s1, (float*)s3);

    // 9-13. V projection
    if (big_ws) {
        ushort* wvh = (ushort*)(ws + 3 * SLOTB + (size_t)8 * 1024 * 1024);
        split_f32<<<1024, blk, 0, stream>>>(Wv, wvh, wvh + WEL, (int)(WEL / 4));
        ushort* vsp = (ushort*)d_out;        // hi [0:32MB), lo [32:64MB)
        split_f32<<<2048, blk, 0, stream>>>(value, vsp, vsp + NEL, (int)(NEL / 4));
        gemm_split<<<gemm_full, gblk, 0, stream>>>(vsp, vsp + NEL, wvh, wvh + WEL,
                                                   bv, s1);
    } else {
        ushort* wvh = (ushort*)((char*)d_out + (size_t)32 * 1024 * 1024);
        split_f32<<<1024, blk, 0, stream>>>(Wv, wvh, wvh + WEL, (int)(WEL / 4));
        ushort* vsp = (ushort*)d_out;
        for (int hhalf = 0; hhalf < 2; ++hhalf) {
            split_f32<<<2048, blk, 0, stream>>>(value + hhalf * HEL, vsp, vsp + HEL, (int)(HEL / 4));
            gemm_split<<<gemm_half, gblk, 0, stream>>>(vsp, vsp + HEL, wvh, wvh + WEL,
                                                       bv, s1 + hhalf * HEL);
        }
    }

    // 14. correlation forward (Qa=s2, Ka=s3) -> Spart in d_out
    float2* Spart = (float2*)d_out;
    corr_fwd<<<dim3(128, 8), blk, 0, stream>>>((const float*)s2, (const float*)s3, Spart);
    // 15. inverse + top-k + softmax
    corr_inv_topk<<<dim3(128), blk, 0, stream>>>(Spart, dtaus, dw);
    // 16. delayed-V aggregation -> (hi,lo) in s2
    agg_gather<<<dim3(128, 8), blk, 0, stream>>>(s1, dtaus, dw,
                                                 (ushort*)s2, (ushort*)s2 + NEL);
    // 17. Wo split -> s3
    split_f32<<<1024, blk, 0, stream>>>(Wo, (ushort*)s3, (ushort*)s3 + WEL, (int)(WEL / 4));
    // 18. output projection -> d_out
    gemm_split<<<gemm_full, gblk, 0, stream>>>((ushort*)s2, (ushort*)s2 + NEL,
                                               (ushort*)s3, (ushort*)s3 + WEL, bo, out);
}